// Round 10
// baseline (268.585 us; speedup 1.0000x reference)
//
#include <hip/hip_runtime.h>
#include <math.h>

// ---------------------------------------------------------------------------
// Quantized CNN forward (bitwise-exact vs fp32 reference):
//   block_k: maxpool2( quant_act( conv3x3(x, quant_weight(wk)), ak ) )
//   then global max over HxW, then 1x1 conv (10x128).
//
// R24: R23 = 80.7us convs (worse than R19's 76): the cnt-padding dummy
// entries (~46% of taken pairs have cnt=1) added more work than the
// latency they hid. Instruction diet: entry path is near-minimal; STAGING
// is ~35% of issued instructions (5 scalar loads + 5 scalar ds_writes +
// selects per chunk-channel, xNGRP). This round:
//  (1) FLOAT2 STAGING: pair span gx0 = ix0-1+2s is always EVEN (ix0 odd)
//      -> 8B-aligned; W even -> pairs are all-or-nothing in-image. Per
//      channel: 612 pair-slots -> 3/thread: one float2 load + one fused
//      ds_write2_b32 (two const-offset stores, base 40r+s, offsets 0/+20)
//      instead of 5 loads + 5 writes + 5 selects. Odd parity plane shifts
//      +1 (c=-1 -> garbage slot, never read); build_lists re-encodes u0
//      (odd term 21) and partner delta (+21/-20). Tile values at all read
//      positions identical -> bitwise-same output.
//  (2) REVERT padding: pair LDS reads only for real entry pairs (cnt>=2,
//      cnt>=4), scalar remainder; exact accumulation order kept.
//  (3) Keep R23 prefetch placement (issue after sync2, ages thru compute).
// ---------------------------------------------------------------------------

__global__ __launch_bounds__(64)
void prep_zero(unsigned* __restrict__ maxb) {
    if (threadIdx.x < 4) maxb[threadIdx.x] = 0u;
}

__global__ __launch_bounds__(256)
void prep_absmax(const float* __restrict__ w1, const float* __restrict__ w2,
                 const float* __restrict__ w3, const float* __restrict__ wc,
                 unsigned* __restrict__ maxb) {
    const float* srcs[4] = {w1, w2, w3, wc};
    const int    ns[4]   = {32*3*9, 64*32*9, 128*64*9, 10*128};
    const int t = blockIdx.y;
    const float* s = srcs[t];
    const int    N = ns[t];
    float m = 0.f;
    for (int i = blockIdx.x * 256 + threadIdx.x; i < N; i += 16 * 256)
        m = fmaxf(m, fabsf(s[i]));
    #pragma unroll
    for (int o = 32; o > 0; o >>= 1) m = fmaxf(m, __shfl_down(m, o));
    __shared__ float red[4];
    const int lane = threadIdx.x & 63, wid = threadIdx.x >> 6;
    if (lane == 0) red[wid] = m;
    __syncthreads();
    if (threadIdx.x == 0) {
        float mm = fmaxf(fmaxf(red[0], red[1]), fmaxf(red[2], red[3]));
        atomicMax(maxb + t, __float_as_uint(mm));  // |w|>=0: uint order == float order
    }
}

// Classifier weights still need real quantized values (ternary * s).
__global__ __launch_bounds__(256)
void prep_qwc(const float* __restrict__ wc, const unsigned* __restrict__ maxb,
              float* __restrict__ qwc) {
    const float sc = fmaxf(__uint_as_float(maxb[3]), 1e-8f);
    const int i = blockIdx.x * 256 + threadIdx.x;
    if (i < 1280) qwc[i] = rintf(wc[i] / sc) * sc;
}

// Compacted nz-tap lists. Per (grp-of-16-co, chunk-of-4-ci) a 36-dword
// header: dwords 0..3 = 16 u8 counts; dwords 4..35 = per-co 4 inline u16
// entries (co c at halfwords 8+4c .. 8+4c+3).
// Entry = sign<<15 | (kc&1)<<14 | u0, with (R24 parity mapping)
//   u0 = cil*1360 + 40*(k/3) + ((k%3)&1 ? 21 : 0) + ((k%3)>>1)
// Partner quad col: pq1 = pq0 + (kc odd ? -20 : +21).
// Entries j>=4 go to pool[(rc*16+c)*32 + (j-4)] (capacity 32; 4+32=36 max).
// Order within a co: cil asc, k asc == the verified accumulation order.
__global__ __launch_bounds__(256)
void build_lists(const float* __restrict__ w1, const float* __restrict__ w2,
                 const float* __restrict__ w3, const unsigned* __restrict__ maxb,
                 unsigned* __restrict__ h1, unsigned short* __restrict__ p1,
                 unsigned* __restrict__ h2, unsigned short* __restrict__ p2,
                 unsigned* __restrict__ h3, unsigned short* __restrict__ p3) {
    const float* wsrc[3] = {w1, w2, w3};
    unsigned*       hs[3] = {h1, h2, h3};
    unsigned short* ps[3] = {p1, p2, p3};
    const int cins[3] = {3, 32, 64};
    const int nch[3]  = {1, 8, 16};
    const int ngc[3]  = {2, 32, 128};       // (Co/16) * nchunk
    const int t = blockIdx.y;
    const float* w = wsrc[t];
    const int CIN = cins[t], NCHUNK = nch[t];
    const int total = ngc[t] * 16;
    const float sc = fmaxf(__uint_as_float(maxb[t]), 1e-8f);
    for (int u = blockIdx.x * 256 + threadIdx.x; u < total; u += 8 * 256) {
        const int c = u & 15, rc = u >> 4;  // rc = grp*NCHUNK + ch
        const int ch = rc % NCHUNK, grp = rc / NCHUNK;
        const int co = grp * 16 + c;
        unsigned* hdr = hs[t] + (size_t)rc * 36;
        unsigned short* inl = (unsigned short*)(hdr + 4);
        unsigned short* ovf = ps[t] + ((size_t)rc * 16 + c) * 32;
        int j = 0;
        for (int cil = 0; cil < 4; ++cil) {
            const int ci = ch * 4 + cil;
            if (ci >= CIN) break;
            for (int k = 0; k < 9; ++k) {
                const float q = rintf(w[(co * CIN + ci) * 9 + k] / sc);
                unsigned sgn;
                if (q > 0.5f)       sgn = 0u;
                else if (q < -0.5f) sgn = 0x8000u;
                else continue;
                const int kr = k / 3, kc = k % 3;
                const unsigned u0 =
                    (unsigned)(cil * 1360 + kr * 40
                               + ((kc & 1) ? 21 : 0) + (kc >> 1));
                const unsigned short e =
                    (unsigned short)(sgn | ((unsigned)(kc & 1) << 14) | u0);
                if (j < 4) inl[c * 4 + j] = e;
                else       ovf[j - 4] = e;
                ++j;
            }
        }
        ((unsigned char*)hdr)[c] = (unsigned char)j;
    }
}

// Load one entry's 2x2 patch into q[0..3] (constant offsets -> ds_read2).
#define LOAD_ENTRY(e, q)                                                   \
    {                                                                      \
        const float* pq0 = TB + ((e) & 0x3fffu);                           \
        const float* pq1 = pq0 + (((e) & 0x4000u) ? -20 : 21);             \
        q[0] = pq0[0]; q[1] = pq1[0]; q[2] = pq0[40]; q[3] = pq1[40];      \
    }
#define FMA_ENTRY(wv, q)                                                   \
    {                                                                      \
        acc[c][0] = fmaf(wv, q[0], acc[c][0]);                             \
        acc[c][1] = fmaf(wv, q[1], acc[c][1]);                             \
        acc[c][2] = fmaf(wv, q[2], acc[c][2]);                             \
        acc[c][3] = fmaf(wv, q[3], acc[c][3]);                             \
    }
#define APPLY_ENTRY(e)                                                     \
    {                                                                      \
        const float wv = ((e) & 0x8000u) ? sNeg : sPos;                    \
        float qo[4];                                                       \
        LOAD_ENTRY(e, qo);                                                 \
        FMA_ENTRY(wv, qo);                                                 \
    }
#define APPLY_PAIR(ea, eb)                                                 \
    {                                                                      \
        const float wva = ((ea) & 0x8000u) ? sNeg : sPos;                  \
        const float wvb = ((eb) & 0x8000u) ? sNeg : sPos;                  \
        float qa[4], qb[4];                                                \
        LOAD_ENTRY(ea, qa);                                                \
        LOAD_ENTRY(eb, qb);                                                \
        FMA_ENTRY(wva, qa);                                                \
        FMA_ENTRY(wvb, qb);                                                \
    }

// Sparse fused conv3x3(pad=1) + maxpool2 + quant_act.
// 16x16 threads over a 16x16 pooled tile (32x32 conv px, 34x34 input tile).
// ci in chunks of 4; float2-pair staging (3 slots/thread/channel), prefetch
// issued AFTER sync2. Parity-split tile rows (stride 40) conflict-free.
template<int CIN, int Co, int LIDX>
__global__ __launch_bounds__(256, 4)
void conv_sparse(const float* __restrict__ in, const unsigned* __restrict__ hdrs,
                 const unsigned short* __restrict__ pool,
                 const unsigned* __restrict__ maxb,
                 const float* __restrict__ alpha_p, float* __restrict__ out,
                 int H, int W) {
    constexpr int NCHUNK = (CIN + 3) / 4;
    constexpr int CCH    = (CIN < 4) ? CIN : 4;
    constexpr int NGRP   = Co / 16;
    const int PH = H >> 1, PW = W >> 1;
    const int tx = threadIdx.x, ty = threadIdx.y;
    const int tid = ty * 16 + tx;
    const int b   = blockIdx.z / NGRP;
    const int grp = blockIdx.z % NGRP;
    const int px  = blockIdx.x * 16 + tx;
    const int py  = blockIdx.y * 16 + ty;
    const int ix0 = blockIdx.x * 32 - 1;       // odd -> pair spans even-aligned
    const int iy0 = blockIdx.y * 32 - 1;

    __shared__ float tile[CCH * 1360];         // parity-split [cil][34 x 40]
    const size_t HW = (size_t)H * W;
    const float* inB = in + (size_t)b * CIN * HW;

    // Pair staging slots: 34 rows x 18 pairs = 612 per plane, 3 per thread.
    // Pair s of row r covers logical cols (2s-1, 2s) = gx (ix0-1+2s, +1):
    // even-aligned float2, all-or-nothing in-image (W even). LDS dest:
    // base 40r+s, words +0 (even plane idx s) and +20 (odd plane idx s).
    int aidx[3], lofs[3];
    #pragma unroll
    for (int i = 0; i < 3; ++i) {
        const int q = tid + 256 * i;
        const int r = q / 18, s = q - r * 18;
        const int gy = iy0 + r, gx = ix0 - 1 + 2 * s;
        const bool ok = (q < 612) && gy >= 0 && gy < H && gx >= 0 && gx < W;
        aidx[i] = ok ? (gy * W + gx) : -1;
        lofs[i] = r * 40 + s;
    }

    float2 v[CCH][3];                           // in-flight staging buffer
    auto load_chunk = [&](int ch0) {
        #pragma unroll
        for (int ch = 0; ch < CCH; ++ch) {
            const float* inC = inB + (size_t)(ch0 + ch) * HW;
            #pragma unroll
            for (int i = 0; i < 3; ++i) {
                float2 t;
                if (aidx[i] >= 0) t = *(const float2*)(inC + aidx[i]);
                else              { t.x = 0.f; t.y = 0.f; }
                v[ch][i] = t;
            }
        }
    };
    auto store_tile = [&]() {
        #pragma unroll
        for (int ch = 0; ch < CCH; ++ch) {
            float* tb = tile + ch * 1360;
            #pragma unroll
            for (int i = 0; i < 3; ++i) {
                if (i < 2 || tid < 100) {       // slot 2 valid iff tid+512<612
                    float* p = tb + lofs[i];
                    p[0]  = v[ch][i].x;         // even plane idx s
                    p[20] = v[ch][i].y;         // odd  plane idx s (write2 fuse)
                }
            }
        }
    };

    // +-s in SGPRs: exact (s = fmax(absmax,1e-8); -s = exact sign flip).
    const float sAbs = fmaxf(__uint_as_float(maxb[LIDX]), 1e-8f);
    const float sPos = __uint_as_float(__builtin_amdgcn_readfirstlane(__float_as_uint(sAbs)));
    const float sNeg = __uint_as_float(__builtin_amdgcn_readfirstlane(__float_as_uint(-sAbs)));

    float acc[16][4];
    #pragma unroll
    for (int c = 0; c < 16; ++c)
        #pragma unroll
        for (int q = 0; q < 4; ++q) acc[c][q] = 0.f;

    // Per-lane read base (logical row 2ty, even-col plane idx tx).
    const float* TB = tile + 80 * ty + tx;

    load_chunk(0);                              // prologue

    #pragma unroll 1
    for (int chunk = 0; chunk < NCHUNK; ++chunk) {
        // Header loads issued first: uniform s_load, ages under store+syncs.
        const unsigned* hdr = hdrs + (size_t)(grp * NCHUNK + chunk) * 36;
        unsigned cntd[4];
        #pragma unroll
        for (int i = 0; i < 4; ++i) cntd[i] = hdr[i];
        unsigned ent[32];
        #pragma unroll
        for (int i = 0; i < 32; ++i) ent[i] = hdr[4 + i];

        __syncthreads();                        // sync1: tile free
        store_tile();                           // v -> tile (counted waits)
        __syncthreads();                        // sync2: writes visible
        if (chunk + 1 < NCHUNK) load_chunk((chunk + 1) * 4);
        // ^ issued AFTER sync2: ages through the whole compute phase; next
        //   sync1's vmcnt(0) drain catches an already-landed prefetch.

        #pragma unroll
        for (int c = 0; c < 16; ++c) {
            const unsigned cnt = (cntd[c >> 2] >> ((c & 3) * 8)) & 0xffu;
            if (!cnt) continue;                 // uniform pair skip
            const unsigned w0 = ent[2 * c];
            const unsigned e0 = w0 & 0xffffu;
            if (cnt >= 2) {                     // real pair: 2-deep reads
                APPLY_PAIR(e0, w0 >> 16);
                if (cnt == 3) {
                    APPLY_ENTRY(ent[2 * c + 1] & 0xffffu);
                } else if (cnt >= 4) {
                    const unsigned w1 = ent[2 * c + 1];
                    APPLY_PAIR(w1 & 0xffffu, w1 >> 16);
                    if (cnt > 4) {              // rare
                        const unsigned short* pp =
                            pool + ((size_t)(grp * NCHUNK + chunk) * 16 + c) * 32;
                        #pragma unroll 1
                        for (int j = 4; j < (int)cnt; ++j) {
                            const unsigned e = pp[j - 4];
                            APPLY_ENTRY(e);
                        }
                    }
                }
            } else {
                APPLY_ENTRY(e0);                // cnt == 1 (most common)
            }
        }
    }

    if (py < PH && px < PW) {
        const float alpha = *alpha_p;
        const float scale = alpha / 3.0f;       // 2^ABITS - 1 = 3
        #pragma unroll
        for (int c = 0; c < 16; ++c) {
            const float m = fmaxf(fmaxf(acc[c][0], acc[c][1]),
                                  fmaxf(acc[c][2], acc[c][3]));
            const float y = fminf(fmaxf(m, 0.f), alpha);
            out[(((size_t)b * Co + grp * 16 + c) * PH + py) * PW + px] =
                rintf(y / scale) * scale;
        }
    }
}

// One wave per (channel, batch): global max over 28x28.
__global__ __launch_bounds__(64)
void gmax_kernel(const float* __restrict__ h3, float* __restrict__ g) {
    const int c = blockIdx.x, b = blockIdx.y;
    const float* p = h3 + ((size_t)b * 128 + c) * 784;
    float m = -INFINITY;
    for (int i = threadIdx.x; i < 784; i += 64) m = fmaxf(m, p[i]);
    #pragma unroll
    for (int o = 32; o > 0; o >>= 1) m = fmaxf(m, __shfl_down(m, o));
    if (threadIdx.x == 0) g[b * 128 + c] = m;
}

// 1x1 conv 128->10 per batch (same k-ascending FMA order as round 1).
__global__ __launch_bounds__(128)
void classify_kernel(const float* __restrict__ g, const float* __restrict__ qwc,
                     float* __restrict__ out) {
    const int b = blockIdx.x;
    __shared__ float gg[128];
    gg[threadIdx.x] = g[b * 128 + threadIdx.x];
    __syncthreads();
    if (threadIdx.x < 10) {
        float s = 0.f;
        for (int k = 0; k < 128; ++k) s += qwc[threadIdx.x * 128 + k] * gg[k];
        out[b * 10 + threadIdx.x] = s;
    }
}

extern "C" void kernel_launch(void* const* d_in, const int* in_sizes, int n_in,
                              void* d_out, int out_size, void* d_ws, size_t ws_size,
                              hipStream_t stream) {
    const float* x  = (const float*)d_in[0];
    const float* w1 = (const float*)d_in[1];
    const float* w2 = (const float*)d_in[2];
    const float* w3 = (const float*)d_in[3];
    const float* wc = (const float*)d_in[4];
    const float* a1 = (const float*)d_in[5];
    const float* a2 = (const float*)d_in[6];
    const float* a3 = (const float*)d_in[7];

    float* ws = (float*)d_ws;
    size_t o = 0;
    float*    qwc  = ws + o; o += 1280;
    unsigned* maxb = (unsigned*)(ws + o); o += 4;
    float*    g    = ws + o; o += 32 * 128;
    unsigned*       h1 = (unsigned*)(ws + o);       o += 2   * 36;   // hdrs
    unsigned short* p1 = (unsigned short*)(ws + o); o += 2   * 16 * 16;  // 32 hw/co
    unsigned*       h2 = (unsigned*)(ws + o);       o += 32  * 36;
    unsigned short* p2 = (unsigned short*)(ws + o); o += 32  * 16 * 16;
    unsigned*       h3 = (unsigned*)(ws + o);       o += 128 * 36;
    unsigned short* p3 = (unsigned short*)(ws + o); o += 128 * 16 * 16;
    float* h1p = ws + o; o += (size_t)32 * 32 * 112 * 112;
    float* h2p = ws + o; o += (size_t)32 * 64 * 56 * 56;
    float* h3p = ws + o; o += (size_t)32 * 128 * 28 * 28;

    prep_zero<<<1, 64, 0, stream>>>(maxb);
    prep_absmax<<<dim3(16, 4), 256, 0, stream>>>(w1, w2, w3, wc, maxb);
    prep_qwc<<<5, 256, 0, stream>>>(wc, maxb, qwc);
    build_lists<<<dim3(8, 3), 256, 0, stream>>>(w1, w2, w3, maxb,
                                                h1, p1, h2, p2, h3, p3);

    // conv1: 3->32, 224x224 -> pooled 112x112. tiles 7x7, z = 32b * 2 grp
    conv_sparse<3, 32, 0><<<dim3(7, 7, 32 * 2), dim3(16, 16), 0, stream>>>(
        x, h1, p1, maxb, a1, h1p, 224, 224);
    // conv2: 32->64, pooled 56x56. tiles 4x4, z = 32b * 4 grp
    conv_sparse<32, 64, 1><<<dim3(4, 4, 32 * 4), dim3(16, 16), 0, stream>>>(
        h1p, h2, p2, maxb, a2, h2p, 112, 112);
    // conv3: 64->128, pooled 28x28. tiles 2x2, z = 32b * 8 grp
    conv_sparse<64, 128, 2><<<dim3(2, 2, 32 * 8), dim3(16, 16), 0, stream>>>(
        h2p, h3, p3, maxb, a3, h3p, 56, 56);

    gmax_kernel<<<dim3(128, 32), 64, 0, stream>>>(h3p, g);
    classify_kernel<<<32, 128, 0, stream>>>(g, qwc, (float*)d_out);
}